// Round 9
// baseline (231.191 us; speedup 1.0000x reference)
//
#include <hip/hip_runtime.h>

// PillarMaxPooling R9: clean 3-stage pipeline from best measured parts.
// Stage 1 moments: R8's named-scalar accumulators (NO local arrays -- every
//   array form R5-R7 spilled ~166-250MB scratch), 77 moments split across
//   lane roles (role=lane&3, quad of lanes shares one point), butterfly over
//   the 16 same-role lanes, 77 atomicAdd/block. Measured spill-free (R8).
// Stage 2 finalize: mean[c]=m1.W, E[h2][c]=W^T M2 W -> affine sc/bi.
// Stage 3 scatter: R7's measured-74us form: half-wave per point, scalar w,
//   relu value, read-filter + zero-skip, 32-lane atomicMax on one 128B row.
// R8's raw-encode+transform epilogue removed: total was 208.6 with ~97us
// unaccounted -- this round falsifies "transform was the mystery" by removal.

#define CMLP 32
#define BN_EPS 1e-3f
#define PSIZE 0.075f
#define XMIN -54.0f
#define YMIN -54.0f
#define CZ   -1.0f   // 0.5*(Z_MIN+Z_MAX)
#define NMOM 77
#define MOMB 2048    // moments blocks

constexpr int tri_i_f(int t) {
  int i = 0, rem = t;
  while (rem >= 11 - i) { rem -= 11 - i; ++i; }
  return i;
}
constexpr int tri_j_f(int t) {
  int i = 0, rem = t;
  while (rem >= 11 - i) { rem -= 11 - i; ++i; }
  return i + rem;
}

__global__ void __launch_bounds__(256) moments_kernel(
    const float* __restrict__ xyz, const float* __restrict__ ptf,
    const int* __restrict__ pil, const int* __restrict__ sidx,
    float* __restrict__ stats, int N) {
  const int tid = threadIdx.x;
  // named scalar accumulators only -- arrays spill on this toolchain (R5-R7)
  float a0=0,a1=0,a2=0,a3=0,a4=0,a5=0,a6=0,a7=0,a8=0,a9=0,a10=0,
        a11=0,a12=0,a13=0,a14=0,a15=0,a16=0,a17=0,a18=0,a19=0;
  const int role = tid & 3;
  const int q0 = (blockIdx.x * 256 + tid) >> 2;  // quad id; 4 lanes share a point
  const int qstride = MOMB * 64;
  for (int p = q0; p < N; p += qstride) {
    int m = sidx[p];
    float cx = fmaf((float)pil[3 * m + 2] + 0.5f, PSIZE, XMIN);
    float cy = fmaf((float)pil[3 * m + 1] + 0.5f, PSIZE, YMIN);
    float x = xyz[3 * p], y = xyz[3 * p + 1], z = xyz[3 * p + 2];
    float g0 = x - cx, g1 = y - cy, g2 = z - CZ, g3 = x, g4 = y, g5 = z;
    float g6 = ptf[5 * p], g7 = ptf[5 * p + 1], g8 = ptf[5 * p + 2],
          g9 = ptf[5 * p + 3], g10 = ptf[5 * p + 4];
    if (role == 0) {        // t 0..19: 11 firsts + (0,0)..(0,8)
      a0+=g0; a1+=g1; a2+=g2; a3+=g3; a4+=g4; a5+=g5; a6+=g6; a7+=g7;
      a8+=g8; a9+=g9; a10+=g10;
      a11=fmaf(g0,g0,a11); a12=fmaf(g0,g1,a12); a13=fmaf(g0,g2,a13);
      a14=fmaf(g0,g3,a14); a15=fmaf(g0,g4,a15); a16=fmaf(g0,g5,a16);
      a17=fmaf(g0,g6,a17); a18=fmaf(g0,g7,a18); a19=fmaf(g0,g8,a19);
    } else if (role == 1) { // t 20..38: (0,9),(0,10),(1,1)..(1,10),(2,2)..(2,8)
      a0=fmaf(g0,g9,a0);  a1=fmaf(g0,g10,a1);
      a2=fmaf(g1,g1,a2);  a3=fmaf(g1,g2,a3);  a4=fmaf(g1,g3,a4);
      a5=fmaf(g1,g4,a5);  a6=fmaf(g1,g5,a6);  a7=fmaf(g1,g6,a7);
      a8=fmaf(g1,g7,a8);  a9=fmaf(g1,g8,a9);  a10=fmaf(g1,g9,a10);
      a11=fmaf(g1,g10,a11);
      a12=fmaf(g2,g2,a12); a13=fmaf(g2,g3,a13); a14=fmaf(g2,g4,a14);
      a15=fmaf(g2,g5,a15); a16=fmaf(g2,g6,a16); a17=fmaf(g2,g7,a17);
      a18=fmaf(g2,g8,a18);
    } else if (role == 2) { // t 39..57
      a0=fmaf(g2,g9,a0);  a1=fmaf(g2,g10,a1);
      a2=fmaf(g3,g3,a2);  a3=fmaf(g3,g4,a3);  a4=fmaf(g3,g5,a4);
      a5=fmaf(g3,g6,a5);  a6=fmaf(g3,g7,a6);  a7=fmaf(g3,g8,a7);
      a8=fmaf(g3,g9,a8);  a9=fmaf(g3,g10,a9);
      a10=fmaf(g4,g4,a10); a11=fmaf(g4,g5,a11); a12=fmaf(g4,g6,a12);
      a13=fmaf(g4,g7,a13); a14=fmaf(g4,g8,a14); a15=fmaf(g4,g9,a15);
      a16=fmaf(g4,g10,a16);
      a17=fmaf(g5,g5,a17); a18=fmaf(g5,g6,a18);
    } else {                // t 58..76
      a0=fmaf(g5,g7,a0);  a1=fmaf(g5,g8,a1);  a2=fmaf(g5,g9,a2);
      a3=fmaf(g5,g10,a3);
      a4=fmaf(g6,g6,a4);  a5=fmaf(g6,g7,a5);  a6=fmaf(g6,g8,a6);
      a7=fmaf(g6,g9,a7);  a8=fmaf(g6,g10,a8);
      a9=fmaf(g7,g7,a9);  a10=fmaf(g7,g8,a10); a11=fmaf(g7,g9,a11);
      a12=fmaf(g7,g10,a12);
      a13=fmaf(g8,g8,a13); a14=fmaf(g8,g9,a14); a15=fmaf(g8,g10,a15);
      a16=fmaf(g9,g9,a16); a17=fmaf(g9,g10,a17);
      a18=fmaf(g10,g10,a18);
    }
  }
  // butterfly over the 16 lanes sharing a role (xor bits 2..5)
#define BFLY(D)                                                              \
  a0+=__shfl_xor(a0,D);  a1+=__shfl_xor(a1,D);  a2+=__shfl_xor(a2,D);        \
  a3+=__shfl_xor(a3,D);  a4+=__shfl_xor(a4,D);  a5+=__shfl_xor(a5,D);        \
  a6+=__shfl_xor(a6,D);  a7+=__shfl_xor(a7,D);  a8+=__shfl_xor(a8,D);        \
  a9+=__shfl_xor(a9,D);  a10+=__shfl_xor(a10,D); a11+=__shfl_xor(a11,D);     \
  a12+=__shfl_xor(a12,D); a13+=__shfl_xor(a13,D); a14+=__shfl_xor(a14,D);    \
  a15+=__shfl_xor(a15,D); a16+=__shfl_xor(a16,D); a17+=__shfl_xor(a17,D);    \
  a18+=__shfl_xor(a18,D); a19+=__shfl_xor(a19,D);
  BFLY(4) BFLY(8) BFLY(16) BFLY(32)
#undef BFLY
  __shared__ float smom[4 * 80];
  const int wave = tid >> 6, lane = tid & 63;
  if (lane < 4) {
    float* s = &smom[wave * 80 + lane * 20];
    s[0]=a0; s[1]=a1; s[2]=a2; s[3]=a3; s[4]=a4; s[5]=a5; s[6]=a6; s[7]=a7;
    s[8]=a8; s[9]=a9; s[10]=a10; s[11]=a11; s[12]=a12; s[13]=a13; s[14]=a14;
    s[15]=a15; s[16]=a16; s[17]=a17; s[18]=a18; s[19]=a19;
  }
  __syncthreads();
  if (tid < NMOM) {
    int base = (tid < 20) ? 0 : ((tid < 39) ? 20 : ((tid < 58) ? 39 : 58));
    int r = (tid < 20) ? 0 : ((tid < 39) ? 1 : ((tid < 58) ? 2 : 3));
    int k = tid - base;
    float s = smom[r * 20 + k] + smom[80 + r * 20 + k] +
              smom[160 + r * 20 + k] + smom[240 + r * 20 + k];
    atomicAdd(&stats[tid], s);  // 2048 adds per address: negligible
  }
}

__global__ void finalize_kernel(const float* __restrict__ gamma,
                                const float* __restrict__ beta,
                                const float* __restrict__ W1,
                                float* __restrict__ stats, float invN) {
  int c = threadIdx.x;
  if (c < CMLP) {
    float mean = 0.f;
#pragma unroll
    for (int k = 0; k < 11; k++) mean = fmaf(W1[k * CMLP + c], stats[k], mean);
    mean *= invN;
    float e2 = 0.f;
#pragma unroll
    for (int t = 0; t < 66; t++) {
      int i = tri_i_f(t), j = tri_j_f(t);
      float coef = (i == j) ? 1.f : 2.f;
      e2 = fmaf(coef * W1[i * CMLP + c] * W1[j * CMLP + c], stats[11 + t], e2);
    }
    e2 *= invN;
    float var = e2 - mean * mean;                 // biased, like jnp.var
    float sc = gamma[c] * rsqrtf(var + BN_EPS);
    stats[80 + c] = sc;                           // scale
    stats[112 + c] = beta[c] - mean * sc;         // bias
  }
}

__global__ void __launch_bounds__(256) scatter_kernel(
    const float* __restrict__ xyz, const float* __restrict__ ptf,
    const float* __restrict__ W1, const int* __restrict__ pil,
    const int* __restrict__ sidx, const float* __restrict__ affine,
    float* __restrict__ out, int N) {
  const int c = threadIdx.x & 31;
  const float w0 = W1[0 * CMLP + c], w1 = W1[1 * CMLP + c];
  const float w2 = W1[2 * CMLP + c], w3 = W1[3 * CMLP + c];
  const float w4 = W1[4 * CMLP + c], w5 = W1[5 * CMLP + c];
  const float w6 = W1[6 * CMLP + c], w7 = W1[7 * CMLP + c];
  const float w8 = W1[8 * CMLP + c], w9 = W1[9 * CMLP + c];
  const float w10 = W1[10 * CMLP + c];
  const float sc = affine[c];
  const float bi = affine[CMLP + c];
  // half-wave per point; 32 lanes issue the same addresses -> HW broadcast
  const int hw0 = (blockIdx.x * blockDim.x + threadIdx.x) >> 5;
  const int nhw = (gridDim.x * blockDim.x) >> 5;
  int p = hw0;
  int m = (p < N) ? sidx[p] : 0;
  while (p < N) {
    const int pn = p + nhw;
    const int mn = (pn < N) ? sidx[pn] : 0;  // prefetch: breaks dep chain
    float cx = fmaf((float)pil[3 * m + 2] + 0.5f, PSIZE, XMIN);
    float cy = fmaf((float)pil[3 * m + 1] + 0.5f, PSIZE, YMIN);
    float x = xyz[3 * p], y = xyz[3 * p + 1], z = xyz[3 * p + 2];
    float h = (x - cx) * w0;
    h = fmaf(y - cy, w1, h);
    h = fmaf(z - CZ, w2, h);
    h = fmaf(x, w3, h);
    h = fmaf(y, w4, h);
    h = fmaf(z, w5, h);
    h = fmaf(ptf[5 * p + 0], w6, h);
    h = fmaf(ptf[5 * p + 1], w7, h);
    h = fmaf(ptf[5 * p + 2], w8, h);
    h = fmaf(ptf[5 * p + 3], w9, h);
    h = fmaf(ptf[5 * p + 4], w10, h);
    float v = fmaxf(fmaf(h, sc, bi), 0.f);
    // read-filter + zero-skip: max monotone -> stale read only causes a
    // redundant atomic. v>=0 & out zeroed -> int order == fp order.
    int* addr = (int*)&out[m * CMLP + c];
    if (__float_as_int(v) > *addr) atomicMax(addr, __float_as_int(v));
    p = pn;
    m = mn;
  }
}

extern "C" void kernel_launch(void* const* d_in, const int* in_sizes, int n_in,
                              void* d_out, int out_size, void* d_ws, size_t ws_size,
                              hipStream_t stream) {
  const float* xyz = (const float*)d_in[0];
  const float* ptf = (const float*)d_in[1];
  const float* W1 = (const float*)d_in[2];
  const float* gamma = (const float*)d_in[3];
  const float* beta = (const float*)d_in[4];
  const int* pil = (const int*)d_in[5];
  const int* sidx = (const int*)d_in[6];
  float* out = (float*)d_out;
  float* stats = (float*)d_ws;  // [0,77) moments; [80,112) scale; [112,144) bias

  int N = in_sizes[0] / 3;

  hipMemsetAsync(stats, 0, 80 * sizeof(float), stream);
  hipMemsetAsync(out, 0, (size_t)out_size * sizeof(float), stream);

  moments_kernel<<<MOMB, 256, 0, stream>>>(xyz, ptf, pil, sidx, stats, N);
  finalize_kernel<<<1, 64, 0, stream>>>(gamma, beta, W1, stats, 1.0f / (float)N);
  scatter_kernel<<<4096, 256, 0, stream>>>(xyz, ptf, W1, pil, sidx, stats + 80,
                                           out, N);
}

// Round 10
// 207.742 us; speedup vs baseline: 1.1129x; 1.1129x over previous
//
#include <hip/hip_runtime.h>

// PillarMaxPooling R10: R8's fused (moments || raw-scatter) -- best measured
// total (208.6 vs R9's 231; a constant ~85us harness overhead exists in ALL
// rounds, so R8's fusion was a real win) -- with the moments half fixed:
// R8/R9 used role=lane&3, so every wave serially executed all 4 exec-masked
// role branches (~76 VALU/iter). Now role=WAVE index: branches are
// wave-uniform (s_cbranch skips 3/4), all 4 waves of a block read the same
// 64-point window (L1-hot; same VMEM inst count). Named scalars only (arrays
// spill on this toolchain, R5-R7). Scatter: raw sign(gamma)*h scatter-max
// (uint monotone encode + read-filter) -- needs no BN stats, so it runs
// concurrently with moments; transform applies relu(|sc|e+bi) after finalize.

#define CMLP 32
#define BN_EPS 1e-3f
#define PSIZE 0.075f
#define XMIN -54.0f
#define YMIN -54.0f
#define CZ   -1.0f   // 0.5*(Z_MIN+Z_MAX)
#define NMOM 77
#define SCATB 4096   // scatter blocks (first in grid -> resident earliest)
#define MOMB 1024    // moments blocks

constexpr int tri_i_f(int t) {
  int i = 0, rem = t;
  while (rem >= 11 - i) { rem -= 11 - i; ++i; }
  return i;
}
constexpr int tri_j_f(int t) {
  int i = 0, rem = t;
  while (rem >= 11 - i) { rem -= 11 - i; ++i; }
  return i + rem;
}

// monotone float<->uint order map; u==0 unreachable from real data -> empty sentinel
__device__ __forceinline__ unsigned enc_f(float x) {
  unsigned b = __float_as_uint(x);
  return (b & 0x80000000u) ? ~b : (b | 0x80000000u);
}
__device__ __forceinline__ float dec_f(unsigned u) {
  unsigned b = (u & 0x80000000u) ? (u & 0x7fffffffu) : ~u;
  return __uint_as_float(b);
}

__global__ void __launch_bounds__(256) fused_kernel(
    const float* __restrict__ xyz, const float* __restrict__ ptf,
    const float* __restrict__ W1, const float* __restrict__ gamma,
    const int* __restrict__ pil, const int* __restrict__ sidx,
    float* __restrict__ stats, unsigned* __restrict__ outenc, int N) {
  const int tid = threadIdx.x;
  if (blockIdx.x < SCATB) {
    // ================= raw scatter-max (no BN stats needed) ==================
    const int c = tid & 31;
    const float w0 = W1[0 * CMLP + c], w1 = W1[1 * CMLP + c];
    const float w2 = W1[2 * CMLP + c], w3 = W1[3 * CMLP + c];
    const float w4 = W1[4 * CMLP + c], w5 = W1[5 * CMLP + c];
    const float w6 = W1[6 * CMLP + c], w7 = W1[7 * CMLP + c];
    const float w8 = W1[8 * CMLP + c], w9 = W1[9 * CMLP + c];
    const float w10 = W1[10 * CMLP + c];
    const float sgn = (gamma[c] < 0.f) ? -1.f : 1.f;  // sign(sc)=sign(gamma)
    const int hw0 = (blockIdx.x * 256 + tid) >> 5;
    const int nhw = (SCATB * 256) >> 5;
    int p = hw0;
    int m = (p < N) ? sidx[p] : 0;
    while (p < N) {
      const int pn = p + nhw;
      const int mn = (pn < N) ? sidx[pn] : 0;  // prefetch breaks dep chain
      float cx = fmaf((float)pil[3 * m + 2] + 0.5f, PSIZE, XMIN);
      float cy = fmaf((float)pil[3 * m + 1] + 0.5f, PSIZE, YMIN);
      float x = xyz[3 * p], y = xyz[3 * p + 1], z = xyz[3 * p + 2];
      float h = (x - cx) * w0;
      h = fmaf(y - cy, w1, h);
      h = fmaf(z - CZ, w2, h);
      h = fmaf(x, w3, h);
      h = fmaf(y, w4, h);
      h = fmaf(z, w5, h);
      h = fmaf(ptf[5 * p + 0], w6, h);
      h = fmaf(ptf[5 * p + 1], w7, h);
      h = fmaf(ptf[5 * p + 2], w8, h);
      h = fmaf(ptf[5 * p + 3], w9, h);
      h = fmaf(ptf[5 * p + 4], w10, h);
      unsigned u = enc_f(sgn * h);
      unsigned* addr = &outenc[m * CMLP + c];
      // read-filter: max monotone -> stale read only causes a redundant atomic
      if (u > *addr) atomicMax(addr, u);
      p = pn;
      m = mn;
    }
  } else {
    // ========= moments: role = WAVE (uniform branches, no serialization) =====
    const int bid = blockIdx.x - SCATB;
    const int lane = tid & 63;
    const int wv = tid >> 6;  // 0..3 == role
    float a0=0,a1=0,a2=0,a3=0,a4=0,a5=0,a6=0,a7=0,a8=0,a9=0,a10=0,
          a11=0,a12=0,a13=0,a14=0,a15=0,a16=0,a17=0,a18=0,a19=0;
    const int stride = MOMB * 64;
    for (int p0 = bid * 64; p0 < N; p0 += stride) {
      int p = p0 + lane;  // all 4 waves read the same 64-point window (L1-hot)
      if (p < N) {
        int m = sidx[p];
        float cx = fmaf((float)pil[3 * m + 2] + 0.5f, PSIZE, XMIN);
        float cy = fmaf((float)pil[3 * m + 1] + 0.5f, PSIZE, YMIN);
        float x = xyz[3 * p], y = xyz[3 * p + 1], z = xyz[3 * p + 2];
        float g0 = x - cx, g1 = y - cy, g2 = z - CZ, g3 = x, g4 = y, g5 = z;
        float g6 = ptf[5 * p], g7 = ptf[5 * p + 1], g8 = ptf[5 * p + 2],
              g9 = ptf[5 * p + 3], g10 = ptf[5 * p + 4];
        if (wv == 0) {        // t 0..19: 11 firsts + (0,0)..(0,8)
          a0+=g0; a1+=g1; a2+=g2; a3+=g3; a4+=g4; a5+=g5; a6+=g6; a7+=g7;
          a8+=g8; a9+=g9; a10+=g10;
          a11=fmaf(g0,g0,a11); a12=fmaf(g0,g1,a12); a13=fmaf(g0,g2,a13);
          a14=fmaf(g0,g3,a14); a15=fmaf(g0,g4,a15); a16=fmaf(g0,g5,a16);
          a17=fmaf(g0,g6,a17); a18=fmaf(g0,g7,a18); a19=fmaf(g0,g8,a19);
        } else if (wv == 1) { // t 20..38: (0,9),(0,10),(1,1)..(1,10),(2,2)..(2,8)
          a0=fmaf(g0,g9,a0);  a1=fmaf(g0,g10,a1);
          a2=fmaf(g1,g1,a2);  a3=fmaf(g1,g2,a3);  a4=fmaf(g1,g3,a4);
          a5=fmaf(g1,g4,a5);  a6=fmaf(g1,g5,a6);  a7=fmaf(g1,g6,a7);
          a8=fmaf(g1,g7,a8);  a9=fmaf(g1,g8,a9);  a10=fmaf(g1,g9,a10);
          a11=fmaf(g1,g10,a11);
          a12=fmaf(g2,g2,a12); a13=fmaf(g2,g3,a13); a14=fmaf(g2,g4,a14);
          a15=fmaf(g2,g5,a15); a16=fmaf(g2,g6,a16); a17=fmaf(g2,g7,a17);
          a18=fmaf(g2,g8,a18);
        } else if (wv == 2) { // t 39..57
          a0=fmaf(g2,g9,a0);  a1=fmaf(g2,g10,a1);
          a2=fmaf(g3,g3,a2);  a3=fmaf(g3,g4,a3);  a4=fmaf(g3,g5,a4);
          a5=fmaf(g3,g6,a5);  a6=fmaf(g3,g7,a6);  a7=fmaf(g3,g8,a7);
          a8=fmaf(g3,g9,a8);  a9=fmaf(g3,g10,a9);
          a10=fmaf(g4,g4,a10); a11=fmaf(g4,g5,a11); a12=fmaf(g4,g6,a12);
          a13=fmaf(g4,g7,a13); a14=fmaf(g4,g8,a14); a15=fmaf(g4,g9,a15);
          a16=fmaf(g4,g10,a16);
          a17=fmaf(g5,g5,a17); a18=fmaf(g5,g6,a18);
        } else {              // t 58..76
          a0=fmaf(g5,g7,a0);  a1=fmaf(g5,g8,a1);  a2=fmaf(g5,g9,a2);
          a3=fmaf(g5,g10,a3);
          a4=fmaf(g6,g6,a4);  a5=fmaf(g6,g7,a5);  a6=fmaf(g6,g8,a6);
          a7=fmaf(g6,g9,a7);  a8=fmaf(g6,g10,a8);
          a9=fmaf(g7,g7,a9);  a10=fmaf(g7,g8,a10); a11=fmaf(g7,g9,a11);
          a12=fmaf(g7,g10,a12);
          a13=fmaf(g8,g8,a13); a14=fmaf(g8,g9,a14); a15=fmaf(g8,g10,a15);
          a16=fmaf(g9,g9,a16); a17=fmaf(g9,g10,a17);
          a18=fmaf(g10,g10,a18);
        }
      }
    }
    // full 64-lane butterfly per wave
#define BFLY(D)                                                              \
  a0+=__shfl_xor(a0,D);  a1+=__shfl_xor(a1,D);  a2+=__shfl_xor(a2,D);        \
  a3+=__shfl_xor(a3,D);  a4+=__shfl_xor(a4,D);  a5+=__shfl_xor(a5,D);        \
  a6+=__shfl_xor(a6,D);  a7+=__shfl_xor(a7,D);  a8+=__shfl_xor(a8,D);        \
  a9+=__shfl_xor(a9,D);  a10+=__shfl_xor(a10,D); a11+=__shfl_xor(a11,D);     \
  a12+=__shfl_xor(a12,D); a13+=__shfl_xor(a13,D); a14+=__shfl_xor(a14,D);    \
  a15+=__shfl_xor(a15,D); a16+=__shfl_xor(a16,D); a17+=__shfl_xor(a17,D);    \
  a18+=__shfl_xor(a18,D); a19+=__shfl_xor(a19,D);
    BFLY(1) BFLY(2) BFLY(4) BFLY(8) BFLY(16) BFLY(32)
#undef BFLY
    __shared__ float smom[4 * 20];
    if (lane == 0) {
      float* s = &smom[wv * 20];
      s[0]=a0; s[1]=a1; s[2]=a2; s[3]=a3; s[4]=a4; s[5]=a5; s[6]=a6; s[7]=a7;
      s[8]=a8; s[9]=a9; s[10]=a10; s[11]=a11; s[12]=a12; s[13]=a13; s[14]=a14;
      s[15]=a15; s[16]=a16; s[17]=a17; s[18]=a18; s[19]=a19;
    }
    __syncthreads();
    if (tid < NMOM) {
      int base = (tid < 20) ? 0 : ((tid < 39) ? 20 : ((tid < 58) ? 39 : 58));
      int r = (tid < 20) ? 0 : ((tid < 39) ? 1 : ((tid < 58) ? 2 : 3));
      atomicAdd(&stats[tid], smom[r * 20 + (tid - base)]);  // 1024/address
    }
  }
}

__global__ void finalize_kernel(const float* __restrict__ gamma,
                                const float* __restrict__ beta,
                                const float* __restrict__ W1,
                                float* __restrict__ stats, float invN) {
  int c = threadIdx.x;
  if (c < CMLP) {
    float mean = 0.f;
#pragma unroll
    for (int k = 0; k < 11; k++) mean = fmaf(W1[k * CMLP + c], stats[k], mean);
    mean *= invN;
    float e2 = 0.f;
#pragma unroll
    for (int t = 0; t < 66; t++) {
      int i = tri_i_f(t), j = tri_j_f(t);
      float coef = (i == j) ? 1.f : 2.f;
      e2 = fmaf(coef * W1[i * CMLP + c] * W1[j * CMLP + c], stats[11 + t], e2);
    }
    e2 *= invN;
    float var = e2 - mean * mean;                 // biased, like jnp.var
    float sc = gamma[c] * rsqrtf(var + BN_EPS);
    stats[80 + c] = sc;                           // scale
    stats[112 + c] = beta[c] - mean * sc;         // bias
  }
}

__global__ void __launch_bounds__(256) transform_kernel(
    unsigned* __restrict__ io, const float* __restrict__ stats, int total) {
  int i = blockIdx.x * 256 + threadIdx.x;
  if (i < total) {
    unsigned u = io[i];
    int c = i & 31;
    float v = 0.f;  // u==0 <=> empty pillar -> 0 (matches max(-inf,0))
    if (u) v = fmaxf(fmaf(fabsf(stats[80 + c]), dec_f(u), stats[112 + c]), 0.f);
    io[i] = __float_as_uint(v);
  }
}

extern "C" void kernel_launch(void* const* d_in, const int* in_sizes, int n_in,
                              void* d_out, int out_size, void* d_ws, size_t ws_size,
                              hipStream_t stream) {
  const float* xyz = (const float*)d_in[0];
  const float* ptf = (const float*)d_in[1];
  const float* W1 = (const float*)d_in[2];
  const float* gamma = (const float*)d_in[3];
  const float* beta = (const float*)d_in[4];
  const int* pil = (const int*)d_in[5];
  const int* sidx = (const int*)d_in[6];
  unsigned* out = (unsigned*)d_out;
  float* stats = (float*)d_ws;  // [0,77) moments; [80,112) scale; [112,144) bias

  int N = in_sizes[0] / 3;

  hipMemsetAsync(stats, 0, 80 * sizeof(float), stream);
  hipMemsetAsync(out, 0, (size_t)out_size * sizeof(unsigned), stream);

  fused_kernel<<<SCATB + MOMB, 256, 0, stream>>>(xyz, ptf, W1, gamma, pil, sidx,
                                                 stats, out, N);
  finalize_kernel<<<1, 64, 0, stream>>>(gamma, beta, W1, stats, 1.0f / (float)N);
  transform_kernel<<<(out_size + 255) / 256, 256, 0, stream>>>(out, stats,
                                                               out_size);
}